// Round 2
// 428.826 us; speedup vs baseline: 1.0071x; 1.0071x over previous
//
#include <hip/hip_runtime.h>

#define GN 8192
#define GF 256
#define SLOPE 0.2f

// Native clang vector types — __builtin_nontemporal_load/store reject the
// HIP_vector_type structs (int4/float4); ext_vector_type works.
typedef int   vint4   __attribute__((ext_vector_type(4)));
typedef float vfloat4 __attribute__((ext_vector_type(4)));

// ---------------------------------------------------------------------------
// e = h @ a  (8192x256 @ 256x2), one 64-lane wave per row; plus block 0
// classifies the adjacency storage encoding once (first 2048 words = start of
// row 0 in every encoding; diagonal + 5% density make it deterministic):
//   mode 0: int32 bools  — all words in {0,1}
//   mode 1: uint8 bools  — some word >1 with (w & 0xFEFEFEFE)==0
//   mode 2: float32      — some word == 0x3F800000 (word 0 is diag -> 1.0f)
// ---------------------------------------------------------------------------
__global__ __launch_bounds__(256) void compute_e_kernel(
        const float* __restrict__ h, const float* __restrict__ a,
        const unsigned int* __restrict__ adjw,
        float* __restrict__ e1, float* __restrict__ e2,
        int* __restrict__ mode) {
    if (blockIdx.x == 0) {
        __shared__ int s_flags;
        if (threadIdx.x == 0) s_flags = 0;
        __syncthreads();
        int f = 0;
        for (int i = threadIdx.x; i < 2048; i += 256) {
            unsigned int w = adjw[i];
            if (w == 0x3F800000u) f |= 2;
            else if (w > 1u && (w & 0xFEFEFEFEu) == 0u) f |= 1;
        }
        if (f) atomicOr(&s_flags, f);
        __syncthreads();
        if (threadIdx.x == 0)
            *mode = (s_flags & 1) ? 1 : ((s_flags & 2) ? 2 : 0);
    }

    int wave = threadIdx.x >> 6;
    int lane = threadIdx.x & 63;
    int row  = blockIdx.x * 4 + wave;

    const float4* h4 = (const float4*)(h + (size_t)row * GF);
    float4 hv = h4[lane];
    const float4* a4 = (const float4*)a;
    float4 av0 = a4[2 * lane];                  // {a[f0,0],a[f0,1],a[f1,0],a[f1,1]}
    float4 av1 = a4[2 * lane + 1];

    float d1 = hv.x * av0.x + hv.y * av0.z + hv.z * av1.x + hv.w * av1.z;
    float d2 = hv.x * av0.y + hv.y * av0.w + hv.z * av1.y + hv.w * av1.w;
    #pragma unroll
    for (int off = 32; off; off >>= 1) {
        d1 += __shfl_xor(d1, off);
        d2 += __shfl_xor(d2, off);
    }
    if (lane == 0) {
        e1[row] = d1;
        e2[row] = d2;
    }
}

// ---------------------------------------------------------------------------
// Main: one block (512 threads) per PAIR of rows; each thread owns 16 cols
// (4 vec4) of both rows. e2 is loaded ONCE per column-chunk and reused for
// both rows (halves e2 cache-load instructions + L1/L2 traffic), block count
// halves (4096 launches), and both row reductions share one barrier.
// Phase 1: masked exp into registers + block sums; phase 2: scale + nt store.
// Adjacency streamed once (nontemporal, no reuse); output written once (nt).
// Mask applied by MULTIPLY (words/bytes are {0,1}): no cmp/cndmask.
// Leaky ReLU = fmax(s, 0.2*s) — valid for slope in (0,1).
// No max-subtraction: |e1+e2| <~ 14, exp safe in fp32.
// ---------------------------------------------------------------------------
template <int MODE>
__device__ __forceinline__ void attn_pair_body(
        const void* __restrict__ adjv,
        const float* __restrict__ e1, const float* __restrict__ e2,
        float* __restrict__ out, float* __restrict__ wsum /* [16] */) {
    const int r0  = blockIdx.x * 2;
    const int tid = threadIdx.x;
    const float se1a = e1[r0];
    const float se1b = e1[r0 + 1];
    const size_t vba = (size_t)r0 * 2048;   // vec4 (or uint-word) index, row a
    const size_t vbb = vba + 2048;          // row b

    const float4* e2v = (const float4*)e2;

    float va[16], vb[16];
    float acca = 0.f, accb = 0.f;

    #pragma unroll
    for (int c = 0; c < 4; ++c) {
        const int j4 = c * 512 + tid;            // vec4-of-columns index
        float4 ev = e2v[j4];
        float ma0, ma1, ma2, ma3, mb0, mb1, mb2, mb3;   // 0.0 or 1.0
        if (MODE == 0) {
            vint4 awa = __builtin_nontemporal_load(&((const vint4*)adjv)[vba + j4]);
            vint4 awb = __builtin_nontemporal_load(&((const vint4*)adjv)[vbb + j4]);
            ma0 = (float)awa.x; ma1 = (float)awa.y; ma2 = (float)awa.z; ma3 = (float)awa.w;
            mb0 = (float)awb.x; mb1 = (float)awb.y; mb2 = (float)awb.z; mb3 = (float)awb.w;
        } else if (MODE == 1) {
            unsigned int awa = __builtin_nontemporal_load(&((const unsigned int*)adjv)[vba + j4]);
            unsigned int awb = __builtin_nontemporal_load(&((const unsigned int*)adjv)[vbb + j4]);
            ma0 = (float)(awa & 0xFFu);            // v_cvt_f32_ubyte0
            ma1 = (float)((awa >> 8) & 0xFFu);     // v_cvt_f32_ubyte1
            ma2 = (float)((awa >> 16) & 0xFFu);    // v_cvt_f32_ubyte2
            ma3 = (float)(awa >> 24);              // v_cvt_f32_ubyte3
            mb0 = (float)(awb & 0xFFu);
            mb1 = (float)((awb >> 8) & 0xFFu);
            mb2 = (float)((awb >> 16) & 0xFFu);
            mb3 = (float)(awb >> 24);
        } else {
            vfloat4 awa = __builtin_nontemporal_load(&((const vfloat4*)adjv)[vba + j4]);
            vfloat4 awb = __builtin_nontemporal_load(&((const vfloat4*)adjv)[vbb + j4]);
            ma0 = awa.x; ma1 = awa.y; ma2 = awa.z; ma3 = awa.w;
            mb0 = awb.x; mb1 = awb.y; mb2 = awb.z; mb3 = awb.w;
        }

        float s;
        s = se1a + ev.x; s = fmaxf(s, SLOPE * s); float xa0 = __expf(s) * ma0;
        s = se1a + ev.y; s = fmaxf(s, SLOPE * s); float xa1 = __expf(s) * ma1;
        s = se1a + ev.z; s = fmaxf(s, SLOPE * s); float xa2 = __expf(s) * ma2;
        s = se1a + ev.w; s = fmaxf(s, SLOPE * s); float xa3 = __expf(s) * ma3;
        s = se1b + ev.x; s = fmaxf(s, SLOPE * s); float xb0 = __expf(s) * mb0;
        s = se1b + ev.y; s = fmaxf(s, SLOPE * s); float xb1 = __expf(s) * mb1;
        s = se1b + ev.z; s = fmaxf(s, SLOPE * s); float xb2 = __expf(s) * mb2;
        s = se1b + ev.w; s = fmaxf(s, SLOPE * s); float xb3 = __expf(s) * mb3;

        va[c * 4 + 0] = xa0; va[c * 4 + 1] = xa1;
        va[c * 4 + 2] = xa2; va[c * 4 + 3] = xa3;
        vb[c * 4 + 0] = xb0; vb[c * 4 + 1] = xb1;
        vb[c * 4 + 2] = xb2; vb[c * 4 + 3] = xb3;
        acca += (xa0 + xa1) + (xa2 + xa3);
        accb += (xb0 + xb1) + (xb2 + xb3);
    }

    // block reduction: 64-lane butterflies, then 8 wave partials through LDS
    #pragma unroll
    for (int off = 32; off; off >>= 1) {
        acca += __shfl_xor(acca, off);
        accb += __shfl_xor(accb, off);
    }
    if ((tid & 63) == 0) {
        wsum[tid >> 6]     = acca;
        wsum[8 + (tid >> 6)] = accb;
    }
    __syncthreads();
    float ta = 0.f, tb = 0.f;
    #pragma unroll
    for (int w = 0; w < 8; ++w) {                // same-addr LDS broadcast
        ta += wsum[w];
        tb += wsum[8 + w];
    }
    const float inva = 1.0f / ta;
    const float invb = 1.0f / tb;

    vfloat4* outa = (vfloat4*)(out + (size_t)r0 * GN);
    vfloat4* outb = (vfloat4*)(out + ((size_t)r0 + 1) * GN);
    #pragma unroll
    for (int c = 0; c < 4; ++c) {
        vfloat4 oa, ob;
        oa.x = va[c * 4 + 0] * inva; oa.y = va[c * 4 + 1] * inva;
        oa.z = va[c * 4 + 2] * inva; oa.w = va[c * 4 + 3] * inva;
        ob.x = vb[c * 4 + 0] * invb; ob.y = vb[c * 4 + 1] * invb;
        ob.z = vb[c * 4 + 2] * invb; ob.w = vb[c * 4 + 3] * invb;
        __builtin_nontemporal_store(oa, &outa[c * 512 + tid]);
        __builtin_nontemporal_store(ob, &outb[c * 512 + tid]);
    }
}

__global__ __launch_bounds__(512) void attn_pair_kernel(
        const int* __restrict__ mode, const void* __restrict__ adjv,
        const float* __restrict__ e1, const float* __restrict__ e2,
        float* __restrict__ out) {
    __shared__ float wsum[16];
    const int m = *mode;   // uniform across grid (L2 broadcast)
    if (m == 0)      attn_pair_body<0>(adjv, e1, e2, out, wsum);
    else if (m == 1) attn_pair_body<1>(adjv, e1, e2, out, wsum);
    else             attn_pair_body<2>(adjv, e1, e2, out, wsum);
}

extern "C" void kernel_launch(void* const* d_in, const int* in_sizes, int n_in,
                              void* d_out, int out_size, void* d_ws, size_t ws_size,
                              hipStream_t stream) {
    const float* h   = (const float*)d_in[0];
    const void*  adj = (const void*)d_in[1];
    const float* a   = (const float*)d_in[2];
    float* out = (float*)d_out;

    float* e1   = (float*)d_ws;
    float* e2   = e1 + GN;
    int*   mode = (int*)(e2 + GN);

    compute_e_kernel<<<GN / 4, 256, 0, stream>>>(h, a, (const unsigned int*)adj,
                                                 e1, e2, mode);
    attn_pair_kernel<<<GN / 2, 512, 0, stream>>>(mode, adj, e1, e2, out);
}